// Round 4
// baseline (2971.449 us; speedup 1.0000x reference)
//
#include <hip/hip_runtime.h>

// Emulate numpy f32 per-op rounding exactly: no implicit mul+add fusion.
#pragma clang fp contract(off)

typedef unsigned short u16;
typedef unsigned int u32;
typedef unsigned long long u64;

#define BB 512
#define CC 128
#define TT 500
#define NN 512
#define T_TILE 32
#define LSZ 576                        // list capacity: 512 real + 64 pads

#define TBL_BYTES 1050624ull          // 513*512*4
#define CHUNK_ROW_BYTES 1048576ull    // 512*512*4 per timestep
#define ST_ARR_BYTES 1048576ull       // 512*512*4 per state array
#define PAD_OFF (512u << 11)          // byte offset of the all-zero row

// ---------------- prep kernel ----------------
// Transposed weights with a 513th all-zero row used as the padding target so
// sparse loops run in groups of 32 branch-free (adding 0.0f is exact).
__global__ void prep_weights(const float* __restrict__ W2, const float* __restrict__ Wr2,
                             float* __restrict__ Wr2T, float* __restrict__ W2T) {
  int i = blockIdx.x * blockDim.x + threadIdx.x;
  if (i < 513 * 512) {
    int k = i >> 9, n = i & 511;
    Wr2T[i] = (k < NN) ? Wr2[n * NN + k] : 0.0f;
    W2T[i]  = (k < NN) ? W2[n * NN + k] : 0.0f;
  }
}

// ---------------- i1ff GEMM (chunked): i1ff[b][tl][n] = chain_c x[b][c][t]*W1[n][c] ----
// Bit-exact: each output is ONE ascending-c fmaf chain starting at 0.
__global__ void __launch_bounds__(128, 2)
gemm_i1ff(const float* __restrict__ x, const float* __restrict__ W1,
          float* __restrict__ i1ff, int tBeg, int tLen) {
  const int b = blockIdx.x;
  const int tl0 = blockIdx.y * T_TILE;   // chunk-local t of tile start
  const int tid = threadIdx.x;

  __shared__ __align__(16) float xs[CC * T_TILE];  // [c][j], 16 KB
  __shared__ float W1L[NN * 9];          // [n][cc], padded pitch 9 (odd -> conflict-free), 18 KB

  // stage x tile: consecutive threads -> consecutive t (coalesced)
  for (int i = tid; i < CC * T_TILE; i += 128) {
    int c = i >> 5, j = i & 31;
    int tl = tl0 + j;
    xs[c * T_TILE + j] = (tl < tLen) ? x[(b * CC + c) * TT + (tBeg + tl)] : 0.0f;
  }

  float acc[4][T_TILE];
#pragma unroll
  for (int r = 0; r < 4; ++r)
#pragma unroll
    for (int j = 0; j < T_TILE; ++j) acc[r][j] = 0.0f;

  for (int cp = 0; cp < CC / 8; ++cp) {
    __syncthreads();  // guards xs stores (cp==0) and previous-panel reads
    for (int i = tid; i < NN * 8; i += 128) {
      int nn = i >> 3, cc = i & 7;
      W1L[nn * 9 + cc] = W1[nn * CC + cp * 8 + cc];
    }
    __syncthreads();
#pragma unroll
    for (int cc = 0; cc < 8; ++cc) {
      const int c = cp * 8 + cc;
      float w0 = W1L[(tid + 0)   * 9 + cc];
      float w1 = W1L[(tid + 128) * 9 + cc];
      float w2 = W1L[(tid + 256) * 9 + cc];
      float w3 = W1L[(tid + 384) * 9 + cc];
      const float4* xp = (const float4*)(xs + c * T_TILE);
#pragma unroll
      for (int j4 = 0; j4 < T_TILE / 4; ++j4) {
        float4 xq = xp[j4];              // 16B broadcast, conflict-free
        const int j = j4 * 4;
        acc[0][j + 0] = __builtin_fmaf(xq.x, w0, acc[0][j + 0]);
        acc[1][j + 0] = __builtin_fmaf(xq.x, w1, acc[1][j + 0]);
        acc[2][j + 0] = __builtin_fmaf(xq.x, w2, acc[2][j + 0]);
        acc[3][j + 0] = __builtin_fmaf(xq.x, w3, acc[3][j + 0]);
        acc[0][j + 1] = __builtin_fmaf(xq.y, w0, acc[0][j + 1]);
        acc[1][j + 1] = __builtin_fmaf(xq.y, w1, acc[1][j + 1]);
        acc[2][j + 1] = __builtin_fmaf(xq.y, w2, acc[2][j + 1]);
        acc[3][j + 1] = __builtin_fmaf(xq.y, w3, acc[3][j + 1]);
        acc[0][j + 2] = __builtin_fmaf(xq.z, w0, acc[0][j + 2]);
        acc[1][j + 2] = __builtin_fmaf(xq.z, w1, acc[1][j + 2]);
        acc[2][j + 2] = __builtin_fmaf(xq.z, w2, acc[2][j + 2]);
        acc[3][j + 2] = __builtin_fmaf(xq.z, w3, acc[3][j + 2]);
        acc[0][j + 3] = __builtin_fmaf(xq.w, w0, acc[0][j + 3]);
        acc[1][j + 3] = __builtin_fmaf(xq.w, w1, acc[1][j + 3]);
        acc[2][j + 3] = __builtin_fmaf(xq.w, w2, acc[2][j + 3]);
        acc[3][j + 3] = __builtin_fmaf(xq.w, w3, acc[3][j + 3]);
      }
    }
  }

#pragma unroll
  for (int j = 0; j < T_TILE; ++j) {
    int tl = tl0 + j;
    if (tl < tLen) {
      float* o = i1ff + ((size_t)b * tLen + tl) * NN;
      o[tid + 0]   = acc[0][j];
      o[tid + 128] = acc[1][j];
      o[tid + 256] = acc[2][j];
      o[tid + 384] = acc[3][j];
    }
  }
}

// ---------------- sparse row-sum via RAW ASM gathers (bit-exact chain order) ----
// Rounds 1-3 proved hipcc re-fuses C++ gather loads into the serial sum chain
// (VGPR stayed 36-48), leaving one L2 latency per small group.  Raw volatile
// global_load_dword CANNOT be reordered/fused: all 32 loads of a group issue
// back-to-back, one explicit s_waitcnt covers them, the RA must keep 32
// outputs live.  sched_barrier(0) after each waitcnt stops the scheduler from
// hoisting the dependent adds above it (learn_hip rule #18).
// Tables are read-only for the whole kernel -> no memory-ordering hazard.
// Lists carry >=64 zero-row pads so 32-aligned overreads add exact 0.0f.
#define GLD(f, off, bs) \
  asm volatile("global_load_dword %0, %1, %2" : "=v"(f) : "v"(off), "s"(bs))

#define DECL32(P) \
  float P##00, P##01, P##02, P##03, P##04, P##05, P##06, P##07, \
        P##08, P##09, P##10, P##11, P##12, P##13, P##14, P##15, \
        P##16, P##17, P##18, P##19, P##20, P##21, P##22, P##23, \
        P##24, P##25, P##26, P##27, P##28, P##29, P##30, P##31

#define GATHER32(P, BS, LP) do {                                   \
  const uint4 Q0 = *(const uint4*)((LP) + 0);                      \
  const uint4 Q1 = *(const uint4*)((LP) + 4);                      \
  const uint4 Q2 = *(const uint4*)((LP) + 8);                      \
  const uint4 Q3 = *(const uint4*)((LP) + 12);                     \
  const uint4 Q4 = *(const uint4*)((LP) + 16);                     \
  const uint4 Q5 = *(const uint4*)((LP) + 20);                     \
  const uint4 Q6 = *(const uint4*)((LP) + 24);                     \
  const uint4 Q7 = *(const uint4*)((LP) + 28);                     \
  GLD(P##00, Q0.x + n4, BS); GLD(P##01, Q0.y + n4, BS);            \
  GLD(P##02, Q0.z + n4, BS); GLD(P##03, Q0.w + n4, BS);            \
  GLD(P##04, Q1.x + n4, BS); GLD(P##05, Q1.y + n4, BS);            \
  GLD(P##06, Q1.z + n4, BS); GLD(P##07, Q1.w + n4, BS);            \
  GLD(P##08, Q2.x + n4, BS); GLD(P##09, Q2.y + n4, BS);            \
  GLD(P##10, Q2.z + n4, BS); GLD(P##11, Q2.w + n4, BS);            \
  GLD(P##12, Q3.x + n4, BS); GLD(P##13, Q3.y + n4, BS);            \
  GLD(P##14, Q3.z + n4, BS); GLD(P##15, Q3.w + n4, BS);            \
  GLD(P##16, Q4.x + n4, BS); GLD(P##17, Q4.y + n4, BS);            \
  GLD(P##18, Q4.z + n4, BS); GLD(P##19, Q4.w + n4, BS);            \
  GLD(P##20, Q5.x + n4, BS); GLD(P##21, Q5.y + n4, BS);            \
  GLD(P##22, Q5.z + n4, BS); GLD(P##23, Q5.w + n4, BS);            \
  GLD(P##24, Q6.x + n4, BS); GLD(P##25, Q6.y + n4, BS);            \
  GLD(P##26, Q6.z + n4, BS); GLD(P##27, Q6.w + n4, BS);            \
  GLD(P##28, Q7.x + n4, BS); GLD(P##29, Q7.y + n4, BS);            \
  GLD(P##30, Q7.z + n4, BS); GLD(P##31, Q7.w + n4, BS);            \
} while (0)

#define SUM32(P, S) do { \
  S += P##00; S += P##01; S += P##02; S += P##03; \
  S += P##04; S += P##05; S += P##06; S += P##07; \
  S += P##08; S += P##09; S += P##10; S += P##11; \
  S += P##12; S += P##13; S += P##14; S += P##15; \
  S += P##16; S += P##17; S += P##18; S += P##19; \
  S += P##20; S += P##21; S += P##22; S += P##23; \
  S += P##24; S += P##25; S += P##26; S += P##27; \
  S += P##28; S += P##29; S += P##30; S += P##31; } while (0)

// counted waitcnt + mandatory sched fence (rule #18)
#define VMWAIT(N) do { \
  asm volatile("s_waitcnt vmcnt(" #N ")" ::: "memory"); \
  __builtin_amdgcn_sched_barrier(0); } while (0)

__device__ __forceinline__ float sparse32(const float* __restrict__ mat,
                                          const u32* list, int cnt, u32 n4) {
  if (cnt <= 0) return 0.0f;
  float s = 0.0f;
  if (cnt <= 32) {
    DECL32(g);
    GATHER32(g, mat, list);
    VMWAIT(0);
    SUM32(g, s);
  } else if (cnt <= 64) {
    // two groups in flight; vmcnt(32) = wait group-0 while group-1 flies.
    // Safe w.r.t. unknown compiler loads: vmem completes oldest-first and
    // group-0 is oldest, so remaining<=32 implies group-0 done.
    DECL32(g); DECL32(h);
    GATHER32(g, mat, list);
    GATHER32(h, mat, list + 32);
    VMWAIT(32);
    SUM32(g, s);
    VMWAIT(0);
    SUM32(h, s);
  } else {  // rare
    for (int i = 0; i < cnt; i += 32) {
      DECL32(g);
      GATHER32(g, mat, list + i);
      VMWAIT(0);
      SUM32(g, s);
    }
  }
  return s;
}

// position via v_mbcnt (2 VALU); word totals via readfirstlane -> s_bcnt1 (SALU).
// Writes 64 pad entries so 32-aligned group overreads are always covered.
__device__ __forceinline__ void build_list(const u64* words, int mybit, int wave,
                                           u32 nOff, int n, u32* slot, int* cnt) {
  int tot = 0, base = 0;
#pragma unroll
  for (int j = 0; j < 8; ++j) {
    u64 w = words[j];
    u32 lo = __builtin_amdgcn_readfirstlane((u32)w);
    u32 hi = __builtin_amdgcn_readfirstlane((u32)(w >> 32));
    int pj = __popc(lo) + __popc(hi);
    if (j < wave) base += pj;
    tot += pj;
  }
  if (tot) {
    if (mybit) {
      u64 w = words[wave];
      int below = __builtin_amdgcn_mbcnt_hi((u32)(w >> 32),
                    __builtin_amdgcn_mbcnt_lo((u32)w, 0u));
      slot[base + below] = nOff;
    }
    if (n < 64) slot[tot + n] = PAD_OFF;  // pads -> zero row
  }
  if (n == 0) *cnt = tot;
}

// ---------------- chunked recurrent kernel ----------------
__global__ void __launch_bounds__(512, 4)
recur2(const float* __restrict__ i1ff, const float* __restrict__ Wr2T,
       const float* __restrict__ W2T, const float* __restrict__ W4,
       const float* __restrict__ b1, const float* __restrict__ b2,
       const float* __restrict__ br2, const float* __restrict__ b4,
       const float* __restrict__ Vth1, const float* __restrict__ tau1,
       const float* __restrict__ Vth2, const float* __restrict__ tau2,
       const float* __restrict__ tau_out, float* __restrict__ out,
       float* __restrict__ stM1, float* __restrict__ stM2,
       u32* __restrict__ stSC1, u32* __restrict__ stSC2,
       u64* __restrict__ stW, float* __restrict__ stMemo,
       int tBeg, int tLen, int isFirst, int isLast) {
  const int n = threadIdx.x, b = blockIdx.x;
  const int lane = n & 63, wave = n >> 6;
  const u32 n4 = (u32)(n << 2);
  const u32 nOff = (u32)(n << 11);

  __shared__ u64 wordsA[8], wordsB[8];
  __shared__ __align__(16) u32 listA[2][LSZ];
  __shared__ __align__(16) u32 listB[2][LSZ];
  __shared__ int cA[2], cB[2];

  float mem1, mem2;
  int sc1, sc2;
  // readout split: thread 0 owns row 0, thread 64 owns row 1 (parallel serial
  // chains on different waves; each chain's add order identical to before).
  const int ro = n >> 6;
  const bool isRd = (n == 0) || (n == 64);
  float memo = 0.0f;
  if (isFirst) {
    mem1 = 0.0f; mem2 = 0.0f; sc1 = 0; sc2 = 0;
    if (n < 8) wordsA[n] = 0ull;
    else if (n < 16) wordsB[n - 8] = 0ull;
  } else {
    mem1 = stM1[b * NN + n]; mem2 = stM2[b * NN + n];
    sc1 = (int)stSC1[b * NN + n]; sc2 = (int)stSC2[b * NN + n];
    if (n < 8) wordsA[n] = stW[b * 16 + n];
    else if (n < 16) wordsB[n - 8] = stW[b * 16 + n];
    if (isRd) memo = stMemo[b * 2 + ro];
  }
  __syncthreads();
  int sp1 = (int)((wordsA[wave] >> lane) & 1ull);
  int sp2 = (int)((wordsB[wave] >> lane) & 1ull);
  // initial lists into parity slot 0 (tBeg is always even)
  build_list(wordsA, sp1, wave, nOff, n, listA[0], &cA[0]);
  build_list(wordsB, sp2, wave, nOff, n, listB[0], &cB[0]);
  // first in-loop B0 orders these before use

  const float b1v = b1[n], b2v = b2[n], br2v = br2[n];
  const float t1 = tau1[n], t2 = tau2[n];
  const float v1 = Vth1[n], v2 = Vth2[n];
  const float tov = tau_out[ro & 1];
  const float b4v = b4[ro & 1];

  const float* ffp = i1ff + (size_t)b * tLen * NN + n;
  float ffcur = ffp[0];

  for (int t = tBeg; t < tBeg + tLen; ++t) {
    const int tt = t - tBeg;
    const int pp = t & 1, qq = pp ^ 1;
    const int ttn = (tt + 1 < tLen) ? tt + 1 : tt;
    float ffnext = ffp[(size_t)ttn * NN];   // issued pre-barrier, used next iter
    __syncthreads();  // B0

    // ---- layer 1: i1 = (x@W1^T + b1) + (sp1@Wr2^T + br2) ----
    float r1 = sparse32(Wr2T, listA[pp], cA[pp], n4);
    float u1 = ffcur + b1v;
    float w1s = r1 + br2v;
    float i1 = u1 + w1s;
    float a1m = t1 * mem1;
    a1m = sp1 ? 0.0f : a1m;
    float m1 = a1m + i1;
    mem1 = m1;
    const int s1 = (m1 - v1) > 0.0f ? 1 : 0;
    u64 ba = __ballot(s1 != 0);
    if (lane == 0) wordsA[wave] = ba;
    __syncthreads();  // B1

    build_list(wordsA, s1, wave, nOff, n, listA[qq], &cA[qq]);
    __syncthreads();  // B1b

    // ---- layer 2: i2 = (s1@W2^T + b2) + (sp2@Wr2^T + br2) ----
    float ff = sparse32(W2T, listA[qq], cA[qq], n4);
    float u2 = ff + b2v;
    float r2 = sparse32(Wr2T, listB[pp], cB[pp], n4);
    float w2s = r2 + br2v;
    float i2 = u2 + w2s;
    float a2m = t2 * mem2;
    a2m = sp2 ? 0.0f : a2m;
    float m2 = a2m + i2;
    mem2 = m2;
    const int s2 = (m2 - v2) > 0.0f ? 1 : 0;
    u64 bb = __ballot(s2 != 0);
    if (lane == 0) wordsB[wave] = bb;
    sp1 = s1; sp2 = s2; sc1 += s1; sc2 += s2;
    ffcur = ffnext;
    __syncthreads();  // B2

    build_list(wordsB, s2, wave, nOff, n, listB[qq], &cB[qq]);

    // ---- readout: memo = (tau_out*memo) + ((s2@W4^T) + b4) ----
    if (isRd) {
      const float* w4r = W4 + ro * NN;
      float a = 0.0f;  // ascending-k f32 chain (s2 sparse)
#pragma unroll
      for (int w = 0; w < 8; ++w) {
        u64 m = wordsB[w];
        while (m) {
          int k = (w << 6) + __builtin_ctzll(m);
          m &= m - 1ull;
          a += w4r[k];
        }
      }
      float z = tov * memo;
      memo = z + (a + b4v);
      out[(b * 2 + ro) * TT + t] = memo;
    }
  }

  if (isLast) {
    out[BB * 2 * TT + b * NN + n]           = (float)sc1 / 500.0f;
    out[BB * 2 * TT + BB * NN + b * NN + n] = (float)sc2 / 500.0f;
  } else {
    __syncthreads();
    stM1[b * NN + n] = mem1; stM2[b * NN + n] = mem2;
    stSC1[b * NN + n] = (u32)sc1; stSC2[b * NN + n] = (u32)sc2;
    if (n < 8) stW[b * 16 + n] = wordsA[n];
    else if (n < 16) stW[b * 16 + n] = wordsB[n - 8];
    if (isRd) stMemo[b * 2 + ro] = memo;
  }
}

// ---------------- fallback monolithic kernel (tiny ws): no-spill GEMV ----------------
__global__ void __launch_bounds__(512) __attribute__((amdgpu_waves_per_eu(2, 2)))
recur_fb(const float* __restrict__ x, const float* __restrict__ W1,
         const float* __restrict__ Wr2T, const float* __restrict__ W2T,
         const float* __restrict__ W4,
         const float* __restrict__ b1, const float* __restrict__ b2,
         const float* __restrict__ br2, const float* __restrict__ b4,
         const float* __restrict__ Vth1, const float* __restrict__ tau1,
         const float* __restrict__ Vth2, const float* __restrict__ tau2,
         const float* __restrict__ tau_out, float* __restrict__ out) {
  const int n = threadIdx.x, b = blockIdx.x;
  const int lane = n & 63, wave = n >> 6;
  const u32 n4 = (u32)(n << 2);
  const u32 nOff = (u32)(n << 11);

  __shared__ float xs[CC];
  __shared__ u64 wordsA[8], wordsB[8];
  __shared__ __align__(16) u32 listA[2][LSZ];
  __shared__ __align__(16) u32 listB[2][LSZ];
  __shared__ int cA[2], cB[2];

  float w1r[CC];  // fits: waves_per_eu(2,2) -> 256-VGPR budget, no spill
  {
    const float4* wp = (const float4*)(W1 + n * CC);
#pragma unroll
    for (int i = 0; i < CC / 4; ++i) {
      float4 q = wp[i];
      w1r[i * 4 + 0] = q.x; w1r[i * 4 + 1] = q.y;
      w1r[i * 4 + 2] = q.z; w1r[i * 4 + 3] = q.w;
    }
  }

  float mem1 = 0.0f, mem2 = 0.0f;
  const float b1v = b1[n], b2v = b2[n], br2v = br2[n];
  const float t1 = tau1[n], t2 = tau2[n];
  const float v1 = Vth1[n], v2 = Vth2[n];
  const float to0 = tau_out[0], to1 = tau_out[1];
  const float b40 = b4[0], b41 = b4[1];
  int sp1 = 0, sp2 = 0, sc1 = 0, sc2 = 0;
  float memo0 = 0.0f, memo1 = 0.0f;

  if (n == 0) { cA[0] = 0; cB[0] = 0; }

  for (int t = 0; t < TT; ++t) {
    const int pp = t & 1, qq = pp ^ 1;
    if (n < CC) xs[n] = x[(b * CC + n) * TT + t];
    __syncthreads();

    float acc = 0.0f;
#pragma unroll
    for (int c = 0; c < CC; ++c) acc = __builtin_fmaf(xs[c], w1r[c], acc);
    float u1 = acc + b1v;
    float r1 = sparse32(Wr2T, listA[pp], cA[pp], n4);
    float w1s = r1 + br2v;
    float i1 = u1 + w1s;
    float a1m = t1 * mem1;
    a1m = sp1 ? 0.0f : a1m;
    float m1 = a1m + i1;
    mem1 = m1;
    const int s1 = (m1 - v1) > 0.0f ? 1 : 0;
    u64 ba = __ballot(s1 != 0);
    if (lane == 0) wordsA[wave] = ba;
    __syncthreads();

    build_list(wordsA, s1, wave, nOff, n, listA[qq], &cA[qq]);
    __syncthreads();

    float ff = sparse32(W2T, listA[qq], cA[qq], n4);
    float u2 = ff + b2v;
    float r2 = sparse32(Wr2T, listB[pp], cB[pp], n4);
    float w2s = r2 + br2v;
    float i2 = u2 + w2s;
    float a2m = t2 * mem2;
    a2m = sp2 ? 0.0f : a2m;
    float m2 = a2m + i2;
    mem2 = m2;
    const int s2 = (m2 - v2) > 0.0f ? 1 : 0;
    u64 bb = __ballot(s2 != 0);
    if (lane == 0) wordsB[wave] = bb;
    sp1 = s1; sp2 = s2; sc1 += s1; sc2 += s2;
    __syncthreads();

    build_list(wordsB, s2, wave, nOff, n, listB[qq], &cB[qq]);

    if (n == 0) {
      float a0 = 0.0f, a1 = 0.0f;
#pragma unroll
      for (int w = 0; w < 8; ++w) {
        u64 m = wordsB[w];
        while (m) {
          int k = (w << 6) + __builtin_ctzll(m);
          m &= m - 1ull;
          a0 += W4[k];
          a1 += W4[NN + k];
        }
      }
      float z0 = to0 * memo0;
      float z1 = to1 * memo1;
      memo0 = z0 + (a0 + b40);
      memo1 = z1 + (a1 + b41);
      out[(b * 2 + 0) * TT + t] = memo0;
      out[(b * 2 + 1) * TT + t] = memo1;
    }
  }

  out[BB * 2 * TT + b * NN + n]           = (float)sc1 / 500.0f;
  out[BB * 2 * TT + BB * NN + b * NN + n] = (float)sc2 / 500.0f;
}

// ---------------- launcher ----------------
extern "C" void kernel_launch(void* const* d_in, const int* in_sizes, int n_in,
                              void* d_out, int out_size, void* d_ws, size_t ws_size,
                              hipStream_t stream) {
  (void)in_sizes; (void)n_in; (void)out_size;
  const float* x    = (const float*)d_in[0];
  const float* W1   = (const float*)d_in[1];
  const float* b1   = (const float*)d_in[2];
  const float* W2   = (const float*)d_in[3];
  const float* b2   = (const float*)d_in[4];
  const float* Wr2  = (const float*)d_in[5];
  const float* br2  = (const float*)d_in[6];
  // d_in[7..10] = W3,b3,Wr3,br3: dead code w.r.t. outputs — skipped
  const float* W4   = (const float*)d_in[11];
  const float* b4   = (const float*)d_in[12];
  const float* Vth1 = (const float*)d_in[13];
  const float* tau1 = (const float*)d_in[14];
  const float* Vth2 = (const float*)d_in[15];
  const float* tau2 = (const float*)d_in[16];
  const float* tau_out = (const float*)d_in[19];

  char* ws = (char*)d_ws;

  // aux: 2 weight tables + 4 state arrays + ballot words + memo
  const size_t aux = 2 * TBL_BYTES + 4 * ST_ARR_BYTES + 512ull * 16 * 8 + 512ull * 2 * 4;

  int chunkT = 0;
  if (ws_size > aux) {
    long long ct = (long long)((ws_size - aux) / CHUNK_ROW_BYTES);
    if (ct > TT) ct = TT;
    ct &= ~1LL;  // even start for every chunk (list parity)
    if (ct >= 16) chunkT = (int)ct;
  }

  if (chunkT >= 16) {
    char* p = ws;
    float* i1ff = (float*)p;  p += (size_t)chunkT * CHUNK_ROW_BYTES;
    float* Wr2T = (float*)p;  p += TBL_BYTES;
    float* W2T  = (float*)p;  p += TBL_BYTES;
    float* stM1 = (float*)p;  p += ST_ARR_BYTES;
    float* stM2 = (float*)p;  p += ST_ARR_BYTES;
    u32* stSC1  = (u32*)p;    p += ST_ARR_BYTES;
    u32* stSC2  = (u32*)p;    p += ST_ARR_BYTES;
    u64* stW    = (u64*)p;    p += 512ull * 16 * 8;
    float* stMemo = (float*)p;

    hipLaunchKernelGGL(prep_weights, dim3((513 * 512 + 255) / 256), dim3(256), 0, stream,
                       W2, Wr2, Wr2T, W2T);
    for (int t0 = 0; t0 < TT; t0 += chunkT) {
      int len = (TT - t0 < chunkT) ? (TT - t0) : chunkT;
      hipLaunchKernelGGL(gemm_i1ff, dim3(BB, (len + T_TILE - 1) / T_TILE), dim3(128), 0,
                         stream, x, W1, i1ff, t0, len);
      hipLaunchKernelGGL(recur2, dim3(BB), dim3(512), 0, stream,
                         i1ff, Wr2T, W2T, W4, b1, b2, br2, b4,
                         Vth1, tau1, Vth2, tau2, tau_out, (float*)d_out,
                         stM1, stM2, stSC1, stSC2, stW, stMemo,
                         t0, len, (t0 == 0) ? 1 : 0, (t0 + len == TT) ? 1 : 0);
    }
  } else {
    float* Wr2T = (float*)ws;
    float* W2T  = (float*)(ws + TBL_BYTES);
    hipLaunchKernelGGL(prep_weights, dim3((513 * 512 + 255) / 256), dim3(256), 0, stream,
                       W2, Wr2, Wr2T, W2T);
    hipLaunchKernelGGL(recur_fb, dim3(BB), dim3(512), 0, stream,
                       x, W1, Wr2T, W2T, W4, b1, b2, br2, b4,
                       Vth1, tau1, Vth2, tau2, tau_out, (float*)d_out);
  }
}